// Round 21
// baseline (678.926 us; speedup 1.0000x reference)
//
#include <hip/hip_runtime.h>
#include <math.h>

#define M_TOTAL 8192
#define N_RFF   4096
#define K_DIM   512
#define TOPK    409

#define BM 128
#define BN 128
#define BK 16

// global_load_lds: 16B per lane, LDS dest = wave-uniform base + lane*16.
#define GLOAD_LDS16(g, l) __builtin_amdgcn_global_load_lds(                    \
    (const __attribute__((address_space(1))) void*)(g),                        \
    (__attribute__((address_space(3))) void*)(l), 16, 0, 0)

// ---------------------------------------------------------------------------
// GEMM: theta = single ascending-k f32 fmaf chain (bit-frozen ref semantics).
// 128x128 tile, 8x8 acc/thread.  Staging via global_load_lds into a
// chunk-permuted layout: chunk c = q*128 + j*32 + m  holds the float4
// (row = 4m+j, k = kt + q*4 .. +3).  Linear in lane order for the DMA;
// fragment reads are ds_read_b128 at consecutive 16B slots (conflict-free).
// Inner loop: q-groups of 4 k's — per acc element k still strictly ascends,
// so the chain is bit-identical to r16/r19/r20 (absmax 0.0 proven).
// s = theta + b (f32); z = (float)cos((double)s) * f32(SCALE).
// NOTE r18: explicit LDS double-buffering blew VGPR 60->184 -> 850us. Single
// buffer, 2 barriers/tile. VGPR capped <=128 via launch_bounds(256,4).
// ---------------------------------------------------------------------------
__global__ __launch_bounds__(256, 4) void rff_gemm_chain(
    const float* __restrict__ x, const float* __restrict__ W,
    const float* __restrict__ bias, float* __restrict__ zbuf,
    int m0, int rows)
{
    __shared__ float As[BM * BK];   // 8 KB, 512 chunks of 16B
    __shared__ float Bs[BN * BK];   // 8 KB

    const int tid = threadIdx.x;
    const int bm = blockIdx.y * BM, bn = blockIdx.x * BN;
    const int tx = tid & 15, ty = tid >> 4;
    const int w  = tid >> 6, lane = tid & 63;

    // staging assignment: iter t stages chunk c = (w*2+t)*64 + lane
    const float* pA[2];
    const float* pB[2];
    int lbase[2];
    #pragma unroll
    for (int t = 0; t < 2; ++t) {
        const int c = (w * 2 + t) * 64 + lane;
        const int q = c >> 7, j = (c >> 5) & 3, m = c & 31;
        const int row = 4 * m + j;
        int gra = m0 + bm + row; if (gra > M_TOTAL - 1) gra = M_TOTAL - 1;
        pA[t] = x + (size_t)gra * K_DIM + q * 4;           // per-lane global src
        pB[t] = W + (size_t)(bn + row) * K_DIM + q * 4;
        lbase[t] = ((w * 2 + t) * 64) * 4;                 // wave-uniform LDS base
    }

    float acc[8][8];
    #pragma unroll
    for (int i = 0; i < 8; ++i)
        #pragma unroll
        for (int j = 0; j < 8; ++j) acc[i][j] = 0.0f;

    for (int kt = 0; kt < K_DIM; kt += BK) {
        #pragma unroll
        for (int t = 0; t < 2; ++t) {
            GLOAD_LDS16(pA[t] + kt, &As[lbase[t]]);
            GLOAD_LDS16(pB[t] + kt, &Bs[lbase[t]]);
        }
        __syncthreads();   // drains vmcnt (global_load_lds) + barrier

        #pragma unroll
        for (int q = 0; q < 4; ++q) {
            float4 fb[8];
            #pragma unroll
            for (int j = 0; j < 4; ++j) {
                fb[j]     = *(const float4*)&Bs[(q * 128 + j * 32 + tx) * 4];
                fb[4 + j] = *(const float4*)&Bs[(q * 128 + j * 32 + 16 + tx) * 4];
            }
            #pragma unroll
            for (int i = 0; i < 8; ++i) {
                const int ci = (i < 4) ? (q * 128 + i * 32 + ty)
                                       : (q * 128 + (i - 4) * 32 + 16 + ty);
                const float4 fa = *(const float4*)&As[ci * 4];
                #pragma unroll
                for (int kk = 0; kk < 4; ++kk) {           // k ascends: q*4+kk
                    const float av = ((const float*)&fa)[kk];
                    #pragma unroll
                    for (int j = 0; j < 8; ++j)
                        acc[i][j] = fmaf(av, ((const float*)&fb[j])[kk], acc[i][j]);
                }
            }
        }
        __syncthreads();   // all reads done before next tile's DMA overwrites
    }

    const float SC32 = 0.0220970869f;   // f32(sqrt(2/4096)) = 0x3CB504F3

    #pragma unroll
    for (int i = 0; i < 8; ++i) {
        const int rloc = bm + ((i < 4) ? (ty * 4 + i) : (64 + ty * 4 + (i - 4)));
        if (rloc < rows) {
            float* zr = zbuf + (size_t)rloc * N_RFF + bn;
            #pragma unroll
            for (int j = 0; j < 8; ++j) {
                const int c = (j < 4) ? (tx * 4 + j) : (64 + tx * 4 + (j - 4));
                const float s = acc[i][j] + bias[bn + c];   // f32 bias add
                zr[c] = (float)cos((double)s) * SC32;       // CR f32 cos, f32 mul
            }
        }
    }
}

// ---------------------------------------------------------------------------
// Per-row exact top-K via single-pass value buckets (VERBATIM r20 — proven
// absmax 0.0, ~10us): bucket = trunc(|z|*185000) monotone in the f32 key;
// boundary bucket resolved by exact key desc + smallest-index ties.
// ---------------------------------------------------------------------------
#define NBUCKET 4096
#define BSCALE  185000.0f
#define CANDMAX 256

__global__ __launch_bounds__(256) void topk_select(
    const float* __restrict__ zbuf, float* __restrict__ out, int m0)
{
    const int row = blockIdx.x;
    const int tid = threadIdx.x;
    const float* z = zbuf + (size_t)row * N_RFF;

    float v[16];
    unsigned int key[16];
    int bkt[16];
    #pragma unroll
    for (int i = 0; i < 16; ++i) {
        v[i]   = z[tid + i * 256];
        const float av = fabsf(v[i]);
        key[i] = __float_as_uint(av);
        bkt[i] = (int)(av * BSCALE);     // 0..4088 (max |z| = SC32)
    }

    __shared__ unsigned int hist[NBUCKET];   // 16 KB
    __shared__ unsigned int scan[256];
    __shared__ int s_bstar;
    __shared__ int s_kneed;
    __shared__ unsigned int cand_key[CANDMAX];
    __shared__ unsigned int cand_idx[CANDMAX];
    __shared__ int cand_n;
    __shared__ unsigned int keepbits[N_RFF / 32];

    #pragma unroll
    for (int b = 0; b < NBUCKET / 256; ++b) hist[tid + b * 256] = 0u;
    if (tid == 0) cand_n = 0;
    if (tid < N_RFF / 32) keepbits[tid] = 0u;
    __syncthreads();

    #pragma unroll
    for (int i = 0; i < 16; ++i) atomicAdd(&hist[bkt[i]], 1u);
    __syncthreads();

    unsigned int lh[16], ls[16];
    #pragma unroll
    for (int j = 0; j < 16; ++j) lh[j] = hist[tid * 16 + j];
    unsigned int run = 0;
    #pragma unroll
    for (int j = 15; j >= 0; --j) { run += lh[j]; ls[j] = run; }
    const unsigned int T = run;

    scan[tid] = T;
    __syncthreads();
    #pragma unroll
    for (int off = 1; off < 256; off <<= 1) {
        const unsigned int t2 = (tid + off < 256) ? scan[tid + off] : 0u;
        __syncthreads();
        scan[tid] += t2;
        __syncthreads();
    }
    const unsigned int Sexcl = scan[tid] - T;

    #pragma unroll
    for (int j = 0; j < 16; ++j) {
        const unsigned int S = Sexcl + ls[j];
        const unsigned int h = lh[j];
        if (S >= (unsigned)TOPK && S - h < (unsigned)TOPK) {
            s_bstar = tid * 16 + j;
            s_kneed = TOPK - (int)(S - h);
        }
    }
    __syncthreads();
    const int bstar = s_bstar;
    const int kneed = s_kneed;

    #pragma unroll
    for (int i = 0; i < 16; ++i) {
        if (bkt[i] == bstar) {
            const int p = atomicAdd(&cand_n, 1);
            if (p < CANDMAX) { cand_key[p] = key[i]; cand_idx[p] = tid + i * 256; }
        }
    }
    __syncthreads();

    if (tid == 0) {
        int n = cand_n; if (n > CANDMAX) n = CANDMAX;
        for (int a = 1; a < n; ++a) {
            const unsigned int kk = cand_key[a], ii = cand_idx[a];
            int b2 = a - 1;
            while (b2 >= 0 && (cand_key[b2] < kk ||
                               (cand_key[b2] == kk && cand_idx[b2] > ii))) {
                cand_key[b2 + 1] = cand_key[b2];
                cand_idx[b2 + 1] = cand_idx[b2];
                --b2;
            }
            cand_key[b2 + 1] = kk; cand_idx[b2 + 1] = ii;
        }
        int t = kneed; if (t > n) t = n;
        for (int a = 0; a < t; ++a) {
            const unsigned int idx = cand_idx[a];
            keepbits[idx >> 5] |= (1u << (idx & 31));
        }
    }
    __syncthreads();

    float* orow = out + (size_t)(m0 + row) * N_RFF;
    #pragma unroll
    for (int i = 0; i < 16; ++i) {
        const int idx = tid + i * 256;
        const bool keep = (bkt[i] > bstar) ||
                          (bkt[i] == bstar &&
                           ((keepbits[idx >> 5] >> (idx & 31)) & 1u));
        orow[idx] = keep ? v[i] : 0.0f;
    }
}

// ---------------------------------------------------------------------------
extern "C" void kernel_launch(void* const* d_in, const int* in_sizes, int n_in,
                              void* d_out, int out_size, void* d_ws, size_t ws_size,
                              hipStream_t stream)
{
    const float* x    = (const float*)d_in[0];
    const float* W    = (const float*)d_in[1];
    const float* bias = (const float*)d_in[2];
    float* out  = (float*)d_out;
    float* zbuf = (float*)d_ws;

    const size_t row_bytes = (size_t)N_RFF * sizeof(float);
    const size_t maxrows   = row_bytes ? (ws_size / row_bytes) : 0;

    int chunk = (maxrows >= (size_t)M_TOTAL) ? M_TOTAL : (int)maxrows;
    if (chunk < 1) chunk = 1;

    for (int m0 = 0; m0 < M_TOTAL; m0 += chunk) {
        int rows = M_TOTAL - m0;
        if (rows > chunk) rows = chunk;
        dim3 gg(N_RFF / BN, (rows + BM - 1) / BM);
        hipLaunchKernelGGL(rff_gemm_chain, gg, dim3(256), 0, stream,
                           x, W, bias, zbuf, m0, rows);
        hipLaunchKernelGGL(topk_select, dim3(rows), dim3(256), 0, stream,
                           zbuf, out, m0);
    }
}

// Round 22
// 519.079 us; speedup vs baseline: 1.3079x; 1.3079x over previous
//
#include <hip/hip_runtime.h>
#include <math.h>

#define M_TOTAL 8192
#define N_RFF   4096
#define K_DIM   512
#define TOPK    409

#define BM 128
#define BN 128
#define BK 16
#define LDSV (BM + 4)   // 132 floats = 528 B row stride (16B-aligned)

// ---------------------------------------------------------------------------
// GEMM (r16 structure — proven): theta = single ascending-k f32 fmaf chain;
// 128x128 tile, 8x8 acc/thread.  EPILOGUE CHANGE ONLY: writes s = theta+bias
// (f32) — the f64-cos moved to the select kernel to cut peak VGPR (~150->~110)
// and lift occupancy 3->4 waves/SIMD.  Chain semantics bit-identical.
// NOTE r18: explicit dbuf -> VGPR 184, 850us. NOTE r21: launch_bounds(256,4)
// forced spill -> 1GB scratch writes, 720us. No forced caps, no dbuf.
// ---------------------------------------------------------------------------
__global__ __launch_bounds__(256) void rff_gemm_chain(
    const float* __restrict__ x, const float* __restrict__ W,
    const float* __restrict__ bias, float* __restrict__ sbuf,
    int m0, int rows)
{
    __shared__ float As[BK][LDSV];
    __shared__ float Bs[BK][LDSV];

    const int tid = threadIdx.x;
    const int bm = blockIdx.y * BM, bn = blockIdx.x * BN;
    const int tx = tid & 15, ty = tid >> 4;

    float acc[8][8];
    #pragma unroll
    for (int i = 0; i < 8; ++i)
        #pragma unroll
        for (int j = 0; j < 8; ++j) acc[i][j] = 0.0f;

    for (int kt = 0; kt < K_DIM; kt += BK) {
        #pragma unroll
        for (int it = 0; it < 2; ++it) {
            const int i = tid + it * 256;     // 0..511
            const int r = i >> 2;             // 0..127
            const int q = i & 3;              // k-quad
            int gr = m0 + bm + r;             // clamped read; write guarded
            if (gr > M_TOTAL - 1) gr = M_TOTAL - 1;
            const float4 va = *(const float4*)(x + (size_t)gr * K_DIM + kt + q * 4);
            As[q*4+0][r] = va.x;  As[q*4+1][r] = va.y;
            As[q*4+2][r] = va.z;  As[q*4+3][r] = va.w;
            const float4 vb = *(const float4*)(W + (size_t)(bn + r) * K_DIM + kt + q * 4);
            Bs[q*4+0][r] = vb.x;  Bs[q*4+1][r] = vb.y;
            Bs[q*4+2][r] = vb.z;  Bs[q*4+3][r] = vb.w;
        }
        __syncthreads();

        #pragma unroll
        for (int k = 0; k < BK; ++k) {
            float a[8], b[8];
            #pragma unroll
            for (int i = 0; i < 4; ++i) {
                a[i]     = As[k][ty * 4 + i];
                a[4 + i] = As[k][64 + ty * 4 + i];
            }
            #pragma unroll
            for (int j = 0; j < 4; ++j) {
                b[j]     = Bs[k][tx * 4 + j];
                b[4 + j] = Bs[k][64 + tx * 4 + j];
            }
            #pragma unroll
            for (int i = 0; i < 8; ++i)
                #pragma unroll
                for (int j = 0; j < 8; ++j)
                    acc[i][j] = fmaf(a[i], b[j], acc[i][j]);
        }
        __syncthreads();
    }

    #pragma unroll
    for (int i = 0; i < 8; ++i) {
        const int rloc = bm + ((i < 4) ? (ty * 4 + i) : (64 + ty * 4 + (i - 4)));
        if (rloc < rows) {
            float* sr = sbuf + (size_t)rloc * N_RFF + bn;
            #pragma unroll
            for (int j = 0; j < 8; ++j) {
                const int c = (j < 4) ? (tx * 4 + j) : (64 + tx * 4 + (j - 4));
                sr[c] = acc[i][j] + bias[bn + c];   // f32 bias add only
            }
        }
    }
}

// ---------------------------------------------------------------------------
// Per-row exact top-K (r20-proven bucket select, absmax 0.0).  Now computes
// z = (float)cos((double)s) * f32(SCALE) itself (same OCML f64 cos as the old
// GEMM epilogue -> bit-identical values), then: bucket = trunc(|z|*185000)
// monotone in the f32 key; boundary bucket resolved by exact key desc +
// smallest-index ties (lax.top_k semantics).
// ---------------------------------------------------------------------------
#define NBUCKET 4096
#define BSCALE  185000.0f
#define CANDMAX 256

__global__ __launch_bounds__(256) void topk_select(
    const float* __restrict__ sbuf, float* __restrict__ out, int m0)
{
    const int row = blockIdx.x;
    const int tid = threadIdx.x;
    const float* srow = sbuf + (size_t)row * N_RFF;
    const float SC32 = 0.0220970869f;   // f32(sqrt(2/4096)) = 0x3CB504F3

    float v[16];
    unsigned int key[16];
    int bkt[16];
    #pragma unroll
    for (int i = 0; i < 16; ++i) {
        const float s = srow[tid + i * 256];
        v[i] = (float)cos((double)s) * SC32;   // CR f32 cos, f32 scale mul
        const float av = fabsf(v[i]);
        key[i] = __float_as_uint(av);
        bkt[i] = (int)(av * BSCALE);           // 0..4088 (max |z| = SC32)
    }

    __shared__ unsigned int hist[NBUCKET];   // 16 KB
    __shared__ unsigned int scan[256];
    __shared__ int s_bstar;
    __shared__ int s_kneed;
    __shared__ unsigned int cand_key[CANDMAX];
    __shared__ unsigned int cand_idx[CANDMAX];
    __shared__ int cand_n;
    __shared__ unsigned int keepbits[N_RFF / 32];

    #pragma unroll
    for (int b = 0; b < NBUCKET / 256; ++b) hist[tid + b * 256] = 0u;
    if (tid == 0) cand_n = 0;
    if (tid < N_RFF / 32) keepbits[tid] = 0u;
    __syncthreads();

    #pragma unroll
    for (int i = 0; i < 16; ++i) atomicAdd(&hist[bkt[i]], 1u);
    __syncthreads();

    unsigned int lh[16], ls[16];
    #pragma unroll
    for (int j = 0; j < 16; ++j) lh[j] = hist[tid * 16 + j];
    unsigned int run = 0;
    #pragma unroll
    for (int j = 15; j >= 0; --j) { run += lh[j]; ls[j] = run; }
    const unsigned int T = run;

    scan[tid] = T;
    __syncthreads();
    #pragma unroll
    for (int off = 1; off < 256; off <<= 1) {
        const unsigned int t2 = (tid + off < 256) ? scan[tid + off] : 0u;
        __syncthreads();
        scan[tid] += t2;
        __syncthreads();
    }
    const unsigned int Sexcl = scan[tid] - T;

    #pragma unroll
    for (int j = 0; j < 16; ++j) {
        const unsigned int S = Sexcl + ls[j];
        const unsigned int h = lh[j];
        if (S >= (unsigned)TOPK && S - h < (unsigned)TOPK) {
            s_bstar = tid * 16 + j;
            s_kneed = TOPK - (int)(S - h);
        }
    }
    __syncthreads();
    const int bstar = s_bstar;
    const int kneed = s_kneed;

    #pragma unroll
    for (int i = 0; i < 16; ++i) {
        if (bkt[i] == bstar) {
            const int p = atomicAdd(&cand_n, 1);
            if (p < CANDMAX) { cand_key[p] = key[i]; cand_idx[p] = tid + i * 256; }
        }
    }
    __syncthreads();

    if (tid == 0) {
        int n = cand_n; if (n > CANDMAX) n = CANDMAX;
        for (int a = 1; a < n; ++a) {
            const unsigned int kk = cand_key[a], ii = cand_idx[a];
            int b2 = a - 1;
            while (b2 >= 0 && (cand_key[b2] < kk ||
                               (cand_key[b2] == kk && cand_idx[b2] > ii))) {
                cand_key[b2 + 1] = cand_key[b2];
                cand_idx[b2 + 1] = cand_idx[b2];
                --b2;
            }
            cand_key[b2 + 1] = kk; cand_idx[b2 + 1] = ii;
        }
        int t = kneed; if (t > n) t = n;
        for (int a = 0; a < t; ++a) {
            const unsigned int idx = cand_idx[a];
            keepbits[idx >> 5] |= (1u << (idx & 31));
        }
    }
    __syncthreads();

    float* orow = out + (size_t)(m0 + row) * N_RFF;
    #pragma unroll
    for (int i = 0; i < 16; ++i) {
        const int idx = tid + i * 256;
        const bool keep = (bkt[i] > bstar) ||
                          (bkt[i] == bstar &&
                           ((keepbits[idx >> 5] >> (idx & 31)) & 1u));
        orow[idx] = keep ? v[i] : 0.0f;
    }
}

// ---------------------------------------------------------------------------
extern "C" void kernel_launch(void* const* d_in, const int* in_sizes, int n_in,
                              void* d_out, int out_size, void* d_ws, size_t ws_size,
                              hipStream_t stream)
{
    const float* x    = (const float*)d_in[0];
    const float* W    = (const float*)d_in[1];
    const float* bias = (const float*)d_in[2];
    float* out  = (float*)d_out;
    float* sbuf = (float*)d_ws;

    const size_t row_bytes = (size_t)N_RFF * sizeof(float);
    const size_t maxrows   = row_bytes ? (ws_size / row_bytes) : 0;

    int chunk = (maxrows >= (size_t)M_TOTAL) ? M_TOTAL : (int)maxrows;
    if (chunk < 1) chunk = 1;

    for (int m0 = 0; m0 < M_TOTAL; m0 += chunk) {
        int rows = M_TOTAL - m0;
        if (rows > chunk) rows = chunk;
        dim3 gg(N_RFF / BN, (rows + BM - 1) / BM);
        hipLaunchKernelGGL(rff_gemm_chain, gg, dim3(256), 0, stream,
                           x, W, bias, sbuf, m0, rows);
        hipLaunchKernelGGL(topk_select, dim3(rows), dim3(256), 0, stream,
                           sbuf, out, m0);
    }
}